// Round 1
// baseline (69.368 us; speedup 1.0000x reference)
//
#include <hip/hip_runtime.h>
#include <utility>
#include <cstddef>

#define NROWS 16384      // B*S = 4*4096
#define CIN 32
#define X15_N (NROWS*CIN) // 524288
#define POSB 8           // positions per block

// ---------------- compile-time PGA(3,0,1) tables ----------------
// Blade order matches the reference:
// 0:1 1:e0 2:e1 3:e2 4:e3 5:e01 6:e02 7:e03 8:e12 9:e13 10:e23 11:e012 12:e013 13:e023 14:e123 15:e0123
constexpr int BITS_[16] = {0,1,2,4,8,3,5,9,6,10,12,7,11,13,14,15};

constexpr int idx_of(int bits) { int r = -1; for (int i = 0; i < 16; ++i) if (BITS_[i] == bits) r = i; return r; }

constexpr int sign_cat(int a, int b) {
  int sw = 0; a >>= 1;
  while (a) { sw += __builtin_popcount(a & b); a >>= 1; }
  return (sw & 1) ? -1 : 1;
}

constexpr int ds_(int i) { return sign_cat(BITS_[i], 15 ^ BITS_[i]); } // DUAL_SIGN

// GEOM[i,j,*]: nonzero iff blades don't share e0 (e1..e3 square to +1, e0^2=0)
constexpr int geom_s(int i, int j) { int a = BITS_[i], b = BITS_[j]; return ((a & b & 1) == 0) ? sign_cat(a, b) : 0; }
constexpr int geom_m(int i, int j) { return idx_of(BITS_[i] ^ BITS_[j]); }

// Fused join table: join[m] = z15 * sum_{i,j} Xj[i] Yj[j] * TJ(i,j,m)
// chain: dual(X), dual(Y) -> wedge -> dual -> left-multiply by e0123 (only z15 survives)
constexpr int tj_s(int i, int j) {
  int pa = BITS_[15 - i], qa = BITS_[15 - j];      // dual index mapping: X[i] sits at dual slot 15-i with sign ds_(i)
  if (pa & qa) return 0;                           // wedge zero
  int m1 = idx_of(pa ^ qa);                        // line component
  int jb = BITS_[15 - m1];                         // dual(line) slot bits
  if (jb & 1) return 0;                            // e0123 * (blade containing e0) = 0
  return ds_(i) * ds_(j) * sign_cat(pa, qa) * ds_(m1) * sign_cat(15, jb);
}
constexpr int tj_m(int i, int j) {
  int pa = BITS_[15 - i], qa = BITS_[15 - j];
  int m1 = idx_of(pa ^ qa);
  int jb = BITS_[15 - m1];
  return idx_of(15 ^ jb);
}

// ---------------- unrolled sparse bilinear products ----------------
template <int I, int J>
__device__ __forceinline__ void accum_pair(float (&g)[16], float (&jn)[16],
    const float (&xg)[16], const float (&yg)[16],
    const float (&xj)[16], const float (&yj)[16]) {
  constexpr int gs = geom_s(I, J);
  if constexpr (gs != 0) {
    constexpr int m = geom_m(I, J);
    if constexpr (gs > 0) g[m] = fmaf(xg[I],  yg[J], g[m]);
    else                  g[m] = fmaf(xg[I], -yg[J], g[m]);
  }
  constexpr int js = tj_s(I, J);
  if constexpr (js != 0) {
    constexpr int m = tj_m(I, J);
    if constexpr (js > 0) jn[m] = fmaf(xj[I],  yj[J], jn[m]);
    else                  jn[m] = fmaf(xj[I], -yj[J], jn[m]);
  }
}

template <size_t... P>
__device__ __forceinline__ void accum_all(float (&g)[16], float (&jn)[16],
    const float (&xg)[16], const float (&yg)[16],
    const float (&xj)[16], const float (&yj)[16], std::index_sequence<P...>) {
  (accum_pair<(int)(P / 16), (int)(P % 16)>(g, jn, xg, yg, xj, yj), ...);
}

// ---------------- kernel 1: partial sums of x[...,15] ----------------
__global__ __launch_bounds__(256) void reduce_x15(const float* __restrict__ x, float* __restrict__ partials) {
  __shared__ float red[256];
  float s = 0.f;
  for (int i = blockIdx.x * 256 + threadIdx.x; i < X15_N; i += 256 * 256)
    s += x[(long)i * 16 + 15];
  red[threadIdx.x] = s;
  __syncthreads();
  for (int off = 128; off > 0; off >>= 1) {
    if (threadIdx.x < off) red[threadIdx.x] += red[threadIdx.x + off];
    __syncthreads();
  }
  if (threadIdx.x == 0) partials[blockIdx.x] = red[0];
}

// ---------------- kernel 2: z15 finalize + weight pre-sum over n ----------------
// ws layout (floats): [0]=z15, [256..512)=partials, [512..4608)=W4[c][C][4] = {jx,jy,gx,gy}
__global__ __launch_bounds__(256) void prep(const float* __restrict__ partials,
                                            const float* __restrict__ wjx, const float* __restrict__ wjy,
                                            const float* __restrict__ wgx, const float* __restrict__ wgy,
                                            float* __restrict__ wsv) {
  __shared__ float red[256];
  const int tid = threadIdx.x;
  red[tid] = partials[tid];
  __syncthreads();
  for (int off = 128; off > 0; off >>= 1) {
    if (tid < off) red[tid] += red[tid + off];
    __syncthreads();
  }
  if (tid == 0) wsv[0] = red[0] * (1.0f / (float)X15_N);

  for (int f = tid; f < CIN * 32 * 4; f += 256) {
    const int cc = f >> 7, C = (f >> 2) & 31, v = f & 3;
    const float* w = (v == 0) ? wjx : (v == 1) ? wjy : (v == 2) ? wgx : wgy;
    const float* wp = w + ((size_t)C * CIN + cc) * 9;
    float s = 0.f;
#pragma unroll
    for (int n = 0; n < 9; ++n) s += wp[n];
    wsv[512 + f] = s;
  }
}

// ---------------- kernel 3: main ----------------
__global__ __launch_bounds__(256) void ga_main(const float* __restrict__ x,
                                               const float* __restrict__ wsv,
                                               float* __restrict__ out) {
  __shared__ float sW[CIN][32][4];    // [c][C][{jx,jy,gx,gy}]  16 KB
  __shared__ float sU[POSB][CIN][16]; // u = x + x*e0            16 KB

  const int tid = threadIdx.x;

  // stage summed weights
  const float* wsrc = wsv + 512;
#pragma unroll
  for (int f = tid; f < CIN * 32 * 4; f += 256)
    (&sW[0][0][0])[f] = wsrc[f];

  // stage U: one thread per (pos, c)
  const int pos = tid >> 5;
  const int lc  = tid & 31;
  const long row = (long)blockIdx.x * POSB + pos;
  const float4* xp = (const float4*)(x + (row * CIN + lc) * 16);
  const float4 a0 = xp[0], a1 = xp[1], a2 = xp[2], a3 = xp[3];
  float4 u0, u1, u2, u3;
  // u = x + x*e0:  u1+=x0; u5-=x2; u6-=x3; u7-=x4; u11+=x8; u12+=x9; u13+=x10; u15-=x14
  u0.x = a0.x;         u0.y = a0.y + a0.x;  u0.z = a0.z;         u0.w = a0.w;
  u1.x = a1.x;         u1.y = a1.y - a0.z;  u1.z = a1.z - a0.w;  u1.w = a1.w - a1.x;
  u2.x = a2.x;         u2.y = a2.y;         u2.z = a2.z;         u2.w = a2.w + a2.x;
  u3.x = a3.x + a2.y;  u3.y = a3.y + a2.z;  u3.z = a3.z;         u3.w = a3.w - a3.z;
  float4* up = (float4*)&sU[pos][lc][0];
  up[0] = u0; up[1] = u1; up[2] = u2; up[3] = u3;

  const float z15 = wsv[0];
  __syncthreads();

  // GEMV: thread owns (pos, C); 4 shared-U projections
  const int C = lc;
  float xj[16], yj[16], xg[16], yg[16];
#pragma unroll
  for (int m = 0; m < 16; ++m) { xj[m] = 0.f; yj[m] = 0.f; xg[m] = 0.f; yg[m] = 0.f; }

  for (int cc = 0; cc < CIN; ++cc) {
    const float4 w = *(const float4*)&sW[cc][C][0];
    const float4* uu = (const float4*)&sU[pos][cc][0];
    const float4 v0 = uu[0], v1 = uu[1], v2 = uu[2], v3 = uu[3];
    const float um[16] = {v0.x, v0.y, v0.z, v0.w, v1.x, v1.y, v1.z, v1.w,
                          v2.x, v2.y, v2.z, v2.w, v3.x, v3.y, v3.z, v3.w};
#pragma unroll
    for (int m = 0; m < 16; ++m) {
      xj[m] = fmaf(w.x, um[m], xj[m]);
      yj[m] = fmaf(w.y, um[m], yj[m]);
      xg[m] = fmaf(w.z, um[m], xg[m]);
      yg[m] = fmaf(w.w, um[m], yg[m]);
    }
  }

  // sparse bilinear products (compile-time tables, fully unrolled)
  float g[16], jn[16];
#pragma unroll
  for (int m = 0; m < 16; ++m) { g[m] = 0.f; jn[m] = 0.f; }
  accum_all(g, jn, xg, yg, xj, yj, std::make_index_sequence<256>{});
#pragma unroll
  for (int m = 0; m < 16; ++m) jn[m] *= z15;

  // out[row, 0:32, :] = join ; out[row, 32:64, :] = geom
  float* ob = out + (row * 64 + C) * 16;
  float4* oj = (float4*)ob;
  oj[0] = make_float4(jn[0],  jn[1],  jn[2],  jn[3]);
  oj[1] = make_float4(jn[4],  jn[5],  jn[6],  jn[7]);
  oj[2] = make_float4(jn[8],  jn[9],  jn[10], jn[11]);
  oj[3] = make_float4(jn[12], jn[13], jn[14], jn[15]);
  float4* og = (float4*)(ob + 32 * 16);
  og[0] = make_float4(g[0],  g[1],  g[2],  g[3]);
  og[1] = make_float4(g[4],  g[5],  g[6],  g[7]);
  og[2] = make_float4(g[8],  g[9],  g[10], g[11]);
  og[3] = make_float4(g[12], g[13], g[14], g[15]);
}

extern "C" void kernel_launch(void* const* d_in, const int* in_sizes, int n_in,
                              void* d_out, int out_size, void* d_ws, size_t ws_size,
                              hipStream_t stream) {
  const float* x   = (const float*)d_in[0];
  const float* wjx = (const float*)d_in[1];
  const float* wjy = (const float*)d_in[2];
  const float* wgx = (const float*)d_in[3];
  const float* wgy = (const float*)d_in[4];
  float* out = (float*)d_out;
  float* wsv = (float*)d_ws;

  reduce_x15<<<256, 256, 0, stream>>>(x, wsv + 256);
  prep<<<1, 256, 0, stream>>>(wsv + 256, wjx, wjy, wgx, wgy, wsv);
  ga_main<<<NROWS / POSB, 256, 0, stream>>>(x, wsv, out);
}